// Round 1
// baseline (262.889 us; speedup 1.0000x reference)
//
#include <hip/hip_runtime.h>

// LSTM: B=4096, T=1024, I=8, H=4. fp32.
// R6: chain-shortening of the serial scan (the measured wall: 277 cyc/step,
// latency-bound per stream; issue is only ~84 cyc/step).
//  - R5 structure kept: producer/consumer wave split, double-buffered LDS
//    pre-act ring, register-batched ds_read_b128 ping-pong, exp2-domain gates.
//  - R6 chain changes (consumer step):
//    (1) h never materialized on the chain: feedback = sum_k (W[:,k]*og_k)*s_k
//        with s = tanh(c) = 1-2*rc (one fma off rc) and m_k = W*og_k computed
//        OFF-chain (og is ready ~100cyc before rc). DPP broadcasts s and og.
//    (2) Whh accumulation as a tree (fma,fma || mul,fma, add) instead of a
//        4-deep chained fma.
//    (3) c-update rebalanced: c2 = fma(ig, gg2, fg*c2) — the fg*c2 mul
//        overlaps gg2's fma, one level earlier than fma(fg,c2, ig*gg2).
//    Net: removes ~4 dependent VALU levels; 4 transcendentals remain
//    (two sigmoid/tanh pairs are irreducibly on the loop).
// Lane layout: 4 lanes/batch elem; lane j owns hidden j, gate rows
// {j,4+j,8+j,12+j} (PyTorch i,f,g,o). Broadcast via DPP quad_perm.

#define TT 1024
#define II 8
#define CHUNK 32
#define NCHUNK (TT / CHUNK)  // 32
#define ROW (CHUNK * II)     // 256 floats x per stream per chunk
#define SPAD 4

#define L2E 1.4426950408889634f
#define SIG_SCALE (-L2E)       // i,f,o rows
#define G_SCALE (2.0f * L2E)   // g row

typedef float v2f __attribute__((ext_vector_type(2)));

template <int CTRL>
__device__ __forceinline__ float dppf(float v) {
  return __int_as_float(
      __builtin_amdgcn_mov_dpp(__float_as_int(v), CTRL, 0xF, 0xF, true));
}

__device__ __forceinline__ float ex2(float x) {
  return __builtin_amdgcn_exp2f(x);
}
__device__ __forceinline__ float rcp(float x) {
  return __builtin_amdgcn_rcpf(x);
}

#define GLOAD_LDS16(gp, lp)                                   \
  __builtin_amdgcn_global_load_lds(                           \
      (const __attribute__((address_space(1))) void*)(gp),    \
      (__attribute__((address_space(3))) void*)(lp), 16, 0, 0)

__global__ __launch_bounds__(128, 1) void lstm_fused(
    const float* __restrict__ x, const float* __restrict__ W_ih,
    const float* __restrict__ W_hh, const float* __restrict__ b_ih,
    const float* __restrict__ b_hh, const float* __restrict__ fc_w,
    const float* __restrict__ fc_b, float* __restrict__ out, int B) {
  const int tid = threadIdx.x;
  const int wave = tid >> 6;
  const int lane = tid & 63;
  const int j = lane & 3;
  const int grp = lane >> 2;
  const int b = blockIdx.x * 16 + grp;

  __shared__ float xs0[16][ROW + SPAD];
  __shared__ float xs1[16][ROW + SPAD];
  // pre-act ring: [step][stream][j*4 + gate] — lane rw one contiguous float4;
  // wave touches 1KB stride-1 per step (2-way bank alias = free).
  __shared__ float pa0[CHUNK][16][16];
  __shared__ float pa1[CHUNK][16][16];

  if (wave == 0) {
    // ---------------- producer ----------------
    v2f wih01[II], wih23[II];
    v2f bias01, bias23;
#pragma unroll
    for (int k = 0; k < II; ++k) {
      wih01[k] = v2f{SIG_SCALE * W_ih[(0 * 4 + j) * II + k],
                     SIG_SCALE * W_ih[(1 * 4 + j) * II + k]};
      wih23[k] = v2f{G_SCALE * W_ih[(2 * 4 + j) * II + k],
                     SIG_SCALE * W_ih[(3 * 4 + j) * II + k]};
    }
    bias01 = v2f{SIG_SCALE * (b_ih[0 * 4 + j] + b_hh[0 * 4 + j]),
                 SIG_SCALE * (b_ih[1 * 4 + j] + b_hh[1 * 4 + j])};
    bias23 = v2f{G_SCALE * (b_ih[2 * 4 + j] + b_hh[2 * 4 + j]),
                 SIG_SCALE * (b_ih[3 * 4 + j] + b_hh[3 * 4 + j])};

    const size_t blockBase = (size_t)blockIdx.x * 16;

    auto issue = [&](float(*xs)[ROW + SPAD], int t0) {
#pragma unroll
      for (int s = 0; s < 16; ++s) {
        const float* gp =
            x + (blockBase + s) * (TT * II) + (size_t)t0 * II + lane * 4;
        GLOAD_LDS16(gp, &xs[s][0]);
      }
    };

    auto produce = [&](float(*pa)[16][16], const float(*xs)[ROW + SPAD]) {
      const float* row = &xs[grp][0];
#pragma unroll 8
      for (int u = 0; u < CHUNK; ++u) {
        const float4 xa = *(const float4*)(row + u * 8);
        const float4 xb = *(const float4*)(row + u * 8 + 4);
        v2f a01 = bias01, a23 = bias23;
#define XFMA(k, val)                                    \
  {                                                     \
    v2f xv = v2f{(val), (val)};                         \
    a01 = __builtin_elementwise_fma(wih01[k], xv, a01); \
    a23 = __builtin_elementwise_fma(wih23[k], xv, a23); \
  }
        XFMA(0, xa.x) XFMA(1, xa.y) XFMA(2, xa.z) XFMA(3, xa.w)
        XFMA(4, xb.x) XFMA(5, xb.y) XFMA(6, xb.z) XFMA(7, xb.w)
#undef XFMA
        *(float4*)&pa[u][grp][j * 4] = float4{a01.x, a01.y, a23.x, a23.y};
      }
    };

    issue(xs0, 0);
    issue(xs1, CHUNK);
    produce(pa0, xs0);
    __syncthreads();

    for (int ck = 0; ck < NCHUNK; ++ck) {
      if (ck + 1 < NCHUNK)
        produce(((ck + 1) & 1) ? pa1 : pa0, ((ck + 1) & 1) ? xs1 : xs0);
      if (ck + 2 < NCHUNK) issue((ck & 1) ? xs1 : xs0, (ck + 2) * CHUNK);
      __syncthreads();
    }
  } else {
    // ---------------- consumer (serial scan) ----------------
    // W_hh rows pre-scaled to match the producer's pre-act domain.
    v2f whh01[4], whh23[4];
#pragma unroll
    for (int k = 0; k < 4; ++k) {
      whh01[k] = v2f{SIG_SCALE * W_hh[(0 * 4 + j) * 4 + k],
                     SIG_SCALE * W_hh[(1 * 4 + j) * 4 + k]};
      whh23[k] = v2f{G_SCALE * W_hh[(2 * 4 + j) * 4 + k],
                     SIG_SCALE * W_hh[(3 * 4 + j) * 4 + k]};
    }
    // Carried state: c2 = 2*log2e*c, rc = (1-tanh(c))/2, og = sig(o).
    // og=0 makes the first step's feedback exactly zero regardless of rc.
    float c2 = 0.0f, rc = 0.25f, og = 0.0f;

    auto step = [&](float4 g) {
      // ---- feedback from carried (rc, og): h_k = og_k * (1 - 2*rc_k) ----
      const float s = fmaf(rc, -2.0f, 1.0f);  // tanh(c), 1 fma off rc
      const float s0 = dppf<0x00>(s), s1 = dppf<0x55>(s);
      const float s2 = dppf<0xAA>(s), s3 = dppf<0xFF>(s);
      const float o0 = dppf<0x00>(og), o1 = dppf<0x55>(og);
      const float o2 = dppf<0xAA>(og), o3 = dppf<0xFF>(og);
      // m_k = W[:,k]*og_k — og is ready ~100cyc before rc: off-chain.
      const v2f m01_0 = whh01[0] * o0, m01_1 = whh01[1] * o1;
      const v2f m01_2 = whh01[2] * o2, m01_3 = whh01[3] * o3;
      const v2f m23_0 = whh23[0] * o0, m23_1 = whh23[1] * o1;
      const v2f m23_2 = whh23[2] * o2, m23_3 = whh23[3] * o3;
      // tree accumulate: depth 3 (fma,fma || mul,fma; add) vs 4-chained fma
      v2f u01 = __builtin_elementwise_fma(m01_0, v2f{s0, s0}, v2f{g.x, g.y});
      u01 = __builtin_elementwise_fma(m01_1, v2f{s1, s1}, u01);
      v2f v01 = m01_2 * s2;
      v01 = __builtin_elementwise_fma(m01_3, v2f{s3, s3}, v01);
      const v2f a01 = u01 + v01;  // {i', f'} (scaled -log2e)
      v2f u23 = __builtin_elementwise_fma(m23_0, v2f{s0, s0}, v2f{g.z, g.w});
      u23 = __builtin_elementwise_fma(m23_1, v2f{s1, s1}, u23);
      v2f v23 = m23_2 * s2;
      v23 = __builtin_elementwise_fma(m23_3, v2f{s3, s3}, v23);
      const v2f a23 = u23 + v23;  // {g' (2log2e), o' (-log2e)}
      // ---- activations (exp2 domain) ----
      const v2f e01 = v2f{ex2(a01.x), ex2(a01.y)} + 1.0f;
      const v2f e23 = v2f{ex2(a23.x), ex2(a23.y)} + 1.0f;
      const float ig = rcp(e01.x);  // sig(i)
      const float fg = rcp(e01.y);  // sig(f)
      const float rg = rcp(e23.x);  // (1-tanh(g))/2
      og = rcp(e23.y);              // sig(o)
      const float gg2 = fmaf(rg, -2.0f * G_SCALE, G_SCALE);  // 2log2e*tanh(g)
      const float fc = fg * c2;          // overlaps gg2's fma
      c2 = fmaf(ig, gg2, fc);
      rc = rcp(1.0f + ex2(c2));  // (1-tanh(c))/2
    };

    __syncthreads();

    for (int ck = 0; ck < NCHUNK; ++ck) {
      const float(*pa)[16][16] = (ck & 1) ? pa1 : pa0;
      const float* base = &pa[0][grp][j * 4];

      float4 ra[8], rb[8];
#define LOADB(r, u0)                                                \
  {                                                                 \
    _Pragma("unroll") for (int k = 0; k < 8; ++k) (r)[k] =          \
        *(const float4*)(base + (u0 + k) * 256);                    \
  }
#define COMP8(r)                                   \
  { _Pragma("unroll") for (int k = 0; k < 8; ++k) step((r)[k]); }

      LOADB(ra, 0)
      LOADB(rb, 8)
      COMP8(ra)
      LOADB(ra, 16)
      COMP8(rb)
      LOADB(rb, 24)
      COMP8(ra)
      COMP8(rb)
#undef LOADB
#undef COMP8
      __syncthreads();
    }

    // final FC: out[b] = sum_j h_j * fc_w[j] + fc_b,  h = og * tanh(c)
    const float h = og * fmaf(rc, -2.0f, 1.0f);
    float v = h * fc_w[j];
    v += dppf<0xB1>(v);  // quad_perm [1,0,3,2]
    v += dppf<0x4E>(v);  // quad_perm [2,3,0,1]
    if (j == 0 && b < B) out[b] = v + fc_b[0];
  }
}

extern "C" void kernel_launch(void* const* d_in, const int* in_sizes, int n_in,
                              void* d_out, int out_size, void* d_ws,
                              size_t ws_size, hipStream_t stream) {
  const float* x = (const float*)d_in[0];
  const float* W_ih = (const float*)d_in[1];
  const float* W_hh = (const float*)d_in[2];
  const float* b_ih = (const float*)d_in[3];
  const float* b_hh = (const float*)d_in[4];
  const float* fc_w = (const float*)d_in[5];
  const float* fc_b = (const float*)d_in[6];
  float* out = (float*)d_out;

  const int B = in_sizes[0] / (TT * II);
  const int nblocks = (B + 15) / 16;
  lstm_fused<<<nblocks, 128, 0, stream>>>(x, W_ih, W_hh, b_ih, b_hh, fc_w,
                                          fc_b, out, B);
}